// Round 1
// baseline (1674.189 us; speedup 1.0000x reference)
//
#include <hip/hip_runtime.h>
#include <hip/hip_fp16.h>
#include <stdint.h>

// BiLSTM 2-layer, B=64, T=1024, D=H=128.
// Round 7: counters showed scan_kernel at VGPR_Count=48 -- the 64 weight
// words/thread were NOT resident (spilled), so each of the 1024 steps
// re-fetched the whole 128 KB Whh slice from scratch/L2 (~23 TB/s aggregate:
// L2-BW-bound, VALUBusy only 23%). Cause: __launch_bounds__(512) with no
// min-waves arg lets the occupancy heuristic cap VGPRs near 64 and spill.
// We only ever run 1 block/CU (128 blocks, 256 CUs) = 2 waves/EU, so declare
// __launch_bounds__(512, 2) -> 256-VGPR budget; ~100 needed, no spill.
//   gates_t = xg_t + Whh*h_{t-1},  xg = A @ Wih^T + b  (NO recurrence)
// 1) xg precomputed for all timesteps with an MFMA f16 GEMM (16x16x32_f16,
//    B^T layout: both A and B fragments are b128 reads of row-major f16).
// 2) scan keeps only Whh resident: 64 f16x2 words/thread.

#define T_SEQ 1024
#define B_SZ  64
#define M_TOT 65536  // B*T rows

typedef _Float16 h2_t __attribute__((ext_vector_type(2)));
typedef _Float16 f16x8 __attribute__((ext_vector_type(8)));
typedef float f32x4 __attribute__((ext_vector_type(4)));

__device__ inline float dot2(uint32_t a, uint32_t b, float c) {
  return __builtin_amdgcn_fdot2(__builtin_bit_cast(h2_t, a),
                                __builtin_bit_cast(h2_t, b), c, false);
}

__device__ inline uint32_t pack2(float a, float b) {
  uint16_t ua = __builtin_bit_cast(uint16_t, (_Float16)a);
  uint16_t ub = __builtin_bit_cast(uint16_t, (_Float16)b);
  return (uint32_t)ua | ((uint32_t)ub << 16);
}

__device__ inline float sigmoidf_fast(float z) { return 1.0f / (1.0f + __expf(-z)); }

__device__ inline float tanhf_fast(float z) {
  float e = __expf(-2.0f * fabsf(z));
  float r = (1.0f - e) / (1.0f + e);
  return copysignf(r, z);
}

// ---------- prep kernels ----------

// Whh [512][128] f32 -> wh [64 kw][512 g] u32 (f16x2 along k)
__global__ void prep_whh(const float* __restrict__ Whh, uint32_t* __restrict__ dst) {
  int idx = blockIdx.x * 256 + threadIdx.x;  // < 64*512
  int kw = idx >> 9, g = idx & 511;
  dst[idx] = pack2(Whh[g * 128 + 2 * kw], Whh[g * 128 + 2 * kw + 1]);
}

// Wih [512][2*KW] f32 -> Bt [512 g][KW kw] u32 row-major (= B^T rows for MFMA)
template <int KW>
__global__ void prep_bt(const float* __restrict__ Wih, uint32_t* __restrict__ dst) {
  int idx = blockIdx.x * 256 + threadIdx.x;  // < 512*KW
  constexpr int SH = (KW == 64) ? 6 : 7;
  int g = idx >> SH, kw = idx & (KW - 1);
  dst[idx] = pack2(Wih[g * (2 * KW) + 2 * kw], Wih[g * (2 * KW) + 2 * kw + 1]);
}

__global__ void prep_biasc(const float* __restrict__ bih, const float* __restrict__ bhh,
                           float* __restrict__ dst) {
  int idx = blockIdx.x * 256 + threadIdx.x;  // < 512
  if (idx < 512) dst[idx] = bih[idx] + bhh[idx];
}

// x [B,T,128] f32 -> packed f16x2 [M][64] u32
__global__ void prep_x(const float2* __restrict__ x2, uint32_t* __restrict__ xf16) {
  int idx = blockIdx.x * 256 + threadIdx.x;
  float2 v = x2[idx];
  xf16[idx] = pack2(v.x, v.y);
}

// ---------- xg GEMM: xg[cell][m][512] f16 = A[m][:] . Wih_cell^T + bias ----------
// A: [M][KW] u32 (f16x2, row-major). Bt: [1024 n][KW] u32 (n = cell*512+g).
// Grid (16 n-tiles, 1024 m-tiles) x 256 thr. 64x64 tile, 4 waves of 32x32.
template <int KW>
__global__ __launch_bounds__(256) void xg_gemm(
    const uint32_t* __restrict__ A, const uint32_t* __restrict__ Bt,
    const float* __restrict__ biascat, uint16_t* __restrict__ xg) {
  const int n0 = blockIdx.x * 64;
  const int m0 = blockIdx.y * 64;
  const int tid = threadIdx.x;
  __shared__ uint32_t At[64][36];   // stride 36 words: 16B-aligned quads, 2-way banks
  __shared__ uint32_t Bts[64][36];
  const int lr = tid >> 2, lq = tid & 3;
  const int wave = tid >> 6, lane = tid & 63;
  const int wm = wave >> 1, wn = wave & 1;
  const int q = lane >> 4, ln16 = lane & 15;
  f32x4 acc[2][2] = {};
  for (int kb = 0; kb < KW; kb += 16) {
    uint4 av = *(const uint4*)&A[(size_t)(m0 + lr) * KW + kb + lq * 4];
    uint4 bv = *(const uint4*)&Bt[(size_t)(n0 + lr) * KW + kb + lq * 4];
    __syncthreads();  // previous iteration's fragment reads complete
    *(uint4*)&At[lr][lq * 4] = av;
    *(uint4*)&Bts[lr][lq * 4] = bv;
    __syncthreads();
#pragma unroll
    for (int mi = 0; mi < 2; mi++) {
      f16x8 af = *(const f16x8*)&At[wm * 32 + mi * 16 + ln16][q * 4];
#pragma unroll
      for (int ni = 0; ni < 2; ni++) {
        f16x8 bf = *(const f16x8*)&Bts[wn * 32 + ni * 16 + ln16][q * 4];
        acc[mi][ni] = __builtin_amdgcn_mfma_f32_16x16x32_f16(af, bf, acc[mi][ni], 0, 0, 0);
      }
    }
  }
  // D layout (verified m89/m91): col = lane&15, row = (lane>>4)*4 + reg
#pragma unroll
  for (int mi = 0; mi < 2; mi++)
#pragma unroll
    for (int ni = 0; ni < 2; ni++) {
      int n = n0 + wn * 32 + ni * 16 + ln16;
      int cell = n >> 9, g = n & 511;
      float bs = biascat[n];
#pragma unroll
      for (int i = 0; i < 4; i++) {
        int m = m0 + wm * 32 + mi * 16 + q * 4 + i;
        float v = acc[mi][ni][i] + bs;
        xg[((size_t)cell * M_TOT + m) * 512 + g] =
            __builtin_bit_cast(uint16_t, (_Float16)v);
      }
    }
}

// ---------- scan: gates_t = xg_t + Whh.h_{t-1}, K = 64 words of h only ----------
// 128 WGs (dir*64+b) x 512 thr; thread (j=tid&127, p=tid>>7) computes gate rows
// {j+128r} over h-span [p*16, p*16+16). wh2: [2 dir][64 kw][512 g] u32.
// __launch_bounds__(512, 2): we run exactly 1 block/CU (128 blocks on 256 CUs)
// = 2 waves/EU, so allow the full 256-VGPR budget -> weights stay resident.
template <bool FINAL>
__global__ __launch_bounds__(512, 2) void scan_kernel(
    const uint16_t* __restrict__ xg, const uint32_t* __restrict__ wh2,
    uint16_t* __restrict__ hout, float* __restrict__ fout) {
  const int tid = threadIdx.x;
  const int j = tid & 127;
  const int p = tid >> 7;
  const int b = blockIdx.x & 63;
  const int dir = blockIdx.x >> 6;

  __shared__ __align__(16) uint32_t hbuf[2][64];  // [parity][h f16x2]
  __shared__ float psum[16][128];                 // [r*4+p][j]
  __shared__ float gatesL[4][128];                // [r][j]

  // Whh slice: 4 rows x 16 words = 64 VGPRs.
  uint32_t wq[4][16];
  {
    const uint32_t* wp = wh2 + (size_t)dir * 64 * 512;
#pragma unroll
    for (int r = 0; r < 4; r++)
#pragma unroll
      for (int w = 0; w < 16; w++) wq[r][w] = wp[(p * 16 + w) * 512 + j + 128 * r];
  }
#pragma unroll
  for (int r = 0; r < 4; r++)
#pragma unroll
    for (int w = 0; w < 16; w++) asm volatile("" : "+v"(wq[r][w]));

  const uint16_t* xgp = xg + ((size_t)dir * M_TOT + b * T_SEQ) * 512;

  if (tid < 64) hbuf[0][tid] = 0u;
  float c = 0.0f;
  const int t0 = dir ? (T_SEQ - 1) : 0;
  uint16_t xg_cur = xgp[(size_t)t0 * 512 + tid];
  __syncthreads();

  for (int s = 0; s < T_SEQ; s++) {
    const int t = dir ? (T_SEQ - 1 - s) : s;
    const int par = s & 1;

    // prefetch next step's xg (fully coalesced: one u16 per thread)
    uint16_t xg_nxt = 0;
    if (s + 1 < T_SEQ) {
      const int tn = dir ? (t - 1) : (t + 1);
      xg_nxt = xgp[(size_t)tn * 512 + tid];
    }

    // Phase A: partial dots over h-span p (wave-uniform b128 broadcast reads)
    float a0 = 0.f, a1 = 0.f, a2 = 0.f, a3 = 0.f;
    const uint4* ib = (const uint4*)(&hbuf[par][p * 16]);
#pragma unroll
    for (int kk = 0; kk < 4; kk++) {
      uint4 v = ib[kk];
      a0 = dot2(v.x, wq[0][4 * kk + 0], a0);
      a1 = dot2(v.x, wq[1][4 * kk + 0], a1);
      a2 = dot2(v.x, wq[2][4 * kk + 0], a2);
      a3 = dot2(v.x, wq[3][4 * kk + 0], a3);
      a0 = dot2(v.y, wq[0][4 * kk + 1], a0);
      a1 = dot2(v.y, wq[1][4 * kk + 1], a1);
      a2 = dot2(v.y, wq[2][4 * kk + 1], a2);
      a3 = dot2(v.y, wq[3][4 * kk + 1], a3);
      a0 = dot2(v.z, wq[0][4 * kk + 2], a0);
      a1 = dot2(v.z, wq[1][4 * kk + 2], a1);
      a2 = dot2(v.z, wq[2][4 * kk + 2], a2);
      a3 = dot2(v.z, wq[3][4 * kk + 2], a3);
      a0 = dot2(v.w, wq[0][4 * kk + 3], a0);
      a1 = dot2(v.w, wq[1][4 * kk + 3], a1);
      a2 = dot2(v.w, wq[2][4 * kk + 3], a2);
      a3 = dot2(v.w, wq[3][4 * kk + 3], a3);
    }
    psum[0 * 4 + p][j] = a0;
    psum[1 * 4 + p][j] = a1;
    psum[2 * 4 + p][j] = a2;
    psum[3 * 4 + p][j] = a3;
    __syncthreads();

    // Phase B: thread (j,p) reduces gate row j+128p; xg term folded in here.
    {
      float xgv = (float)__builtin_bit_cast(_Float16, xg_cur);
      float ssum = xgv + psum[p * 4 + 0][j] + psum[p * 4 + 1][j] +
                   psum[p * 4 + 2][j] + psum[p * 4 + 3][j];
      gatesL[p][j] = (p == 2) ? tanhf_fast(ssum) : sigmoidf_fast(ssum);
    }
    __syncthreads();

    // Phase C: p==0 updates c,h; writes h (f16) and the layer output.
    if (p == 0) {
      float iv = gatesL[0][j], fv = gatesL[1][j], gv = gatesL[2][j], ov = gatesL[3][j];
      c = fv * c + iv * gv;
      float h = ov * tanhf_fast(c);
      uint16_t hu = __builtin_bit_cast(uint16_t, (_Float16)h);
      ((uint16_t*)(&hbuf[par ^ 1][0]))[j] = hu;
      if (FINAL) {
        fout[(size_t)(b * T_SEQ + t) * 256 + dir * 128 + j] = h;
      } else {
        hout[(size_t)(b * T_SEQ + t) * 256 + dir * 128 + j] = hu;
      }
    }
    xg_cur = xg_nxt;
    __syncthreads();
  }
}

extern "C" void kernel_launch(void* const* d_in, const int* in_sizes, int n_in,
                              void* d_out, int out_size, void* d_ws, size_t ws_size,
                              hipStream_t stream) {
  const float* x = (const float*)d_in[0];
  const float* Wih_fw1 = (const float*)d_in[2];
  const float* Whh_fw1 = (const float*)d_in[3];
  const float* bih_fw1 = (const float*)d_in[4];
  const float* bhh_fw1 = (const float*)d_in[5];
  const float* Wih_bw1 = (const float*)d_in[6];
  const float* Whh_bw1 = (const float*)d_in[7];
  const float* bih_bw1 = (const float*)d_in[8];
  const float* bhh_bw1 = (const float*)d_in[9];
  const float* Wih_fw2 = (const float*)d_in[10];
  const float* Whh_fw2 = (const float*)d_in[11];
  const float* bih_fw2 = (const float*)d_in[12];
  const float* bhh_fw2 = (const float*)d_in[13];
  const float* Wih_bw2 = (const float*)d_in[14];
  const float* Whh_bw2 = (const float*)d_in[15];
  const float* bih_bw2 = (const float*)d_in[16];
  const float* bhh_bw2 = (const float*)d_in[17];

  uint8_t* ws = (uint8_t*)d_ws;
  // ws layout (bytes):
  //   0        : whbuf   [4 cells][64][512] u32     512 KB
  //   524288   : btbuf1  [2*512][64]  u32           256 KB
  //   786432   : btbuf2  [2*512][128] u32           512 KB
  //   1310720  : biascat [2 layers][1024] f32         8 KB
  //   2097152  : xf16    [M][64] u32                 16 MB
  //   18874368 : out1    [M][128] u32 (f16x2)        32 MB
  //   52428800 : xg      [2][M][512] f16            128 MB   (reused L1 then L2)
  uint32_t* whbuf = (uint32_t*)(ws + 0);
  uint32_t* btbuf1 = (uint32_t*)(ws + 524288);
  uint32_t* btbuf2 = (uint32_t*)(ws + 786432);
  float* biascat = (float*)(ws + 1310720);
  uint32_t* xf16 = (uint32_t*)(ws + 2097152);
  uint32_t* out1 = (uint32_t*)(ws + 18874368);
  uint16_t* xgbuf = (uint16_t*)(ws + 52428800);
  float* fout = (float*)d_out;

  // --- weight / bias / input packing ---
  prep_whh<<<128, 256, 0, stream>>>(Whh_fw1, whbuf + 0 * 32768);
  prep_whh<<<128, 256, 0, stream>>>(Whh_bw1, whbuf + 1 * 32768);
  prep_whh<<<128, 256, 0, stream>>>(Whh_fw2, whbuf + 2 * 32768);
  prep_whh<<<128, 256, 0, stream>>>(Whh_bw2, whbuf + 3 * 32768);
  prep_bt<64><<<128, 256, 0, stream>>>(Wih_fw1, btbuf1 + 0);
  prep_bt<64><<<128, 256, 0, stream>>>(Wih_bw1, btbuf1 + 512 * 64);
  prep_bt<128><<<256, 256, 0, stream>>>(Wih_fw2, btbuf2 + 0);
  prep_bt<128><<<256, 256, 0, stream>>>(Wih_bw2, btbuf2 + 512 * 128);
  prep_biasc<<<2, 256, 0, stream>>>(bih_fw1, bhh_fw1, biascat + 0);
  prep_biasc<<<2, 256, 0, stream>>>(bih_bw1, bhh_bw1, biascat + 512);
  prep_biasc<<<2, 256, 0, stream>>>(bih_fw2, bhh_fw2, biascat + 1024);
  prep_biasc<<<2, 256, 0, stream>>>(bih_bw2, bhh_bw2, biascat + 1536);
  prep_x<<<(B_SZ * T_SEQ * 64) / 256, 256, 0, stream>>>((const float2*)x, xf16);

  // --- layer 1: xg GEMM + scan ---
  xg_gemm<64><<<dim3(16, 1024), 256, 0, stream>>>(xf16, btbuf1, biascat, xgbuf);
  scan_kernel<false><<<128, 512, 0, stream>>>(xgbuf, whbuf + 0, (uint16_t*)out1, nullptr);

  // --- layer 2: xg GEMM (reads out1) + scan -> d_out ---
  xg_gemm<128><<<dim3(16, 1024), 256, 0, stream>>>(out1, btbuf2, biascat + 1024, xgbuf);
  scan_kernel<true><<<128, 512, 0, stream>>>(xgbuf, whbuf + 2 * 32768, nullptr, fout);
}

// Round 2
// 1605.599 us; speedup vs baseline: 1.0427x; 1.0427x over previous
//
#include <hip/hip_runtime.h>
#include <hip/hip_fp16.h>
#include <stdint.h>

// BiLSTM 2-layer, B=64, T=1024, D=H=128.
// Round 8: round-7 counters falsified the weight-refetch theory: FETCH_SIZE
// (66 MB) is exactly the xg stream -- no 16.8 GB scratch/L2 weight traffic.
// Weights are AGPR-parked (unified file, VALU reads AGPRs directly); the scan
// is SERIAL-CHAIN bound: 1700 cyc/step = 3 barriers + 2 LDS round trips
// (psum, gatesL) + divergent Phase C, at only 24% VALUBusy.
// Restructure: K-split partners now live in the same QUAD (tid = 4j+p), so
//   - partial-gate reduction = 3 DPP quad_perm ops (no LDS, no barrier)
//   - each lane does ONE gate nonlinearity (sigmoid form; tanh=2*sig(2z)-1),
//     then 4 DPP broadcasts give every lane i,f,g,o; cell update is computed
//     redundantly (bitwise-identically) by all 4 lanes -- no divergence.
//   - only h needs LDS: 1 u16 write + ONE barrier per step (was 3).
// xg is store-side permuted in the GEMM epilogue (gp = ((g&127)<<2)|(g>>7))
// so the quad mapping still loads consecutive u16 (fully coalesced).

#define T_SEQ 1024
#define B_SZ  64
#define M_TOT 65536  // B*T rows

typedef _Float16 h2_t __attribute__((ext_vector_type(2)));
typedef _Float16 f16x8 __attribute__((ext_vector_type(8)));
typedef float f32x4 __attribute__((ext_vector_type(4)));

__device__ inline float dot2(uint32_t a, uint32_t b, float c) {
  return __builtin_amdgcn_fdot2(__builtin_bit_cast(h2_t, a),
                                __builtin_bit_cast(h2_t, b), c, false);
}

__device__ inline uint32_t pack2(float a, float b) {
  uint16_t ua = __builtin_bit_cast(uint16_t, (_Float16)a);
  uint16_t ub = __builtin_bit_cast(uint16_t, (_Float16)b);
  return (uint32_t)ua | ((uint32_t)ub << 16);
}

// DPP quad_perm helper (compile-time ctrl). xor1=0xB1, xor2=0x4E,
// bcast lane q = q*0x55.
template <int CTRL>
__device__ inline float dppf(float v) {
  return __builtin_bit_cast(
      float, __builtin_amdgcn_update_dpp(0, __builtin_bit_cast(int, v), CTRL,
                                         0xF, 0xF, true));
}

// ---------- prep kernels ----------

// Whh [512][128] f32 -> wh [64 kw][512 g] u32 (f16x2 along k)
__global__ void prep_whh(const float* __restrict__ Whh, uint32_t* __restrict__ dst) {
  int idx = blockIdx.x * 256 + threadIdx.x;  // < 64*512
  int kw = idx >> 9, g = idx & 511;
  dst[idx] = pack2(Whh[g * 128 + 2 * kw], Whh[g * 128 + 2 * kw + 1]);
}

// Wih [512][2*KW] f32 -> Bt [512 g][KW kw] u32 row-major (= B^T rows for MFMA)
template <int KW>
__global__ void prep_bt(const float* __restrict__ Wih, uint32_t* __restrict__ dst) {
  int idx = blockIdx.x * 256 + threadIdx.x;  // < 512*KW
  constexpr int SH = (KW == 64) ? 6 : 7;
  int g = idx >> SH, kw = idx & (KW - 1);
  dst[idx] = pack2(Wih[g * (2 * KW) + 2 * kw], Wih[g * (2 * KW) + 2 * kw + 1]);
}

__global__ void prep_biasc(const float* __restrict__ bih, const float* __restrict__ bhh,
                           float* __restrict__ dst) {
  int idx = blockIdx.x * 256 + threadIdx.x;  // < 512
  if (idx < 512) dst[idx] = bih[idx] + bhh[idx];
}

// x [B,T,128] f32 -> packed f16x2 [M][64] u32
__global__ void prep_x(const float2* __restrict__ x2, uint32_t* __restrict__ xf16) {
  int idx = blockIdx.x * 256 + threadIdx.x;
  float2 v = x2[idx];
  xf16[idx] = pack2(v.x, v.y);
}

// ---------- xg GEMM: xg[cell][m][512] f16 = A[m][:] . Wih_cell^T + bias ----------
// A: [M][KW] u32 (f16x2, row-major). Bt: [1024 n][KW] u32 (n = cell*512+g).
// Grid (16 n-tiles, 1024 m-tiles) x 256 thr. 64x64 tile, 4 waves of 32x32.
// Store-side gate permutation: gp = ((g&127)<<2)|(g>>7) so the scan's quad
// thread map (tid = 4j+p -> gate row j+128p) loads consecutive u16.
template <int KW>
__global__ __launch_bounds__(256) void xg_gemm(
    const uint32_t* __restrict__ A, const uint32_t* __restrict__ Bt,
    const float* __restrict__ biascat, uint16_t* __restrict__ xg) {
  const int n0 = blockIdx.x * 64;
  const int m0 = blockIdx.y * 64;
  const int tid = threadIdx.x;
  __shared__ uint32_t At[64][36];   // stride 36 words: 16B-aligned quads, 2-way banks
  __shared__ uint32_t Bts[64][36];
  const int lr = tid >> 2, lq = tid & 3;
  const int wave = tid >> 6, lane = tid & 63;
  const int wm = wave >> 1, wn = wave & 1;
  const int q = lane >> 4, ln16 = lane & 15;
  f32x4 acc[2][2] = {};
  for (int kb = 0; kb < KW; kb += 16) {
    uint4 av = *(const uint4*)&A[(size_t)(m0 + lr) * KW + kb + lq * 4];
    uint4 bv = *(const uint4*)&Bt[(size_t)(n0 + lr) * KW + kb + lq * 4];
    __syncthreads();  // previous iteration's fragment reads complete
    *(uint4*)&At[lr][lq * 4] = av;
    *(uint4*)&Bts[lr][lq * 4] = bv;
    __syncthreads();
#pragma unroll
    for (int mi = 0; mi < 2; mi++) {
      f16x8 af = *(const f16x8*)&At[wm * 32 + mi * 16 + ln16][q * 4];
#pragma unroll
      for (int ni = 0; ni < 2; ni++) {
        f16x8 bf = *(const f16x8*)&Bts[wn * 32 + ni * 16 + ln16][q * 4];
        acc[mi][ni] = __builtin_amdgcn_mfma_f32_16x16x32_f16(af, bf, acc[mi][ni], 0, 0, 0);
      }
    }
  }
  // D layout (verified m89/m91): col = lane&15, row = (lane>>4)*4 + reg
#pragma unroll
  for (int mi = 0; mi < 2; mi++)
#pragma unroll
    for (int ni = 0; ni < 2; ni++) {
      int n = n0 + wn * 32 + ni * 16 + ln16;
      int cell = n >> 9, g = n & 511;
      int gp = ((g & 127) << 2) | (g >> 7);  // quad-interleaved gate index
      float bs = biascat[n];
#pragma unroll
      for (int i = 0; i < 4; i++) {
        int m = m0 + wm * 32 + mi * 16 + q * 4 + i;
        float v = acc[mi][ni][i] + bs;
        xg[((size_t)cell * M_TOT + m) * 512 + gp] =
            __builtin_bit_cast(uint16_t, (_Float16)v);
      }
    }
}

// ---------- scan: gates_t = xg_t + Whh.h_{t-1} ----------
// 128 WGs (dir*64+b) x 512 thr. Thread (j = tid>>2, p = tid&3) accumulates
// gate rows {j+128r | r=0..3} over h-words [p*16, p*16+16). Quad transpose-
// reduce leaves lane p with the full sum of its OWN gate (row j+128p); one
// exp+rcp per lane; 4 DPP broadcasts; redundant-but-identical cell update.
// One barrier per step (h broadcast through 512B LDS double buffer).
template <bool FINAL>
__global__ __launch_bounds__(512, 2) void scan_kernel(
    const uint16_t* __restrict__ xg, const uint32_t* __restrict__ wh2,
    uint16_t* __restrict__ hout, float* __restrict__ fout) {
  const int tid = threadIdx.x;
  const int j = tid >> 2;  // hidden unit 0..127
  const int p = tid & 3;   // quarter-K span / gate selector
  const int b = blockIdx.x & 63;
  const int dir = blockIdx.x >> 6;

  __shared__ __align__(16) uint32_t hbuf[2][64];  // [parity][h f16x2]

  // Whh slice: rows {j+128r}, k-words [p*16, p*16+16) = 64 u32.
  uint32_t wq[4][16];
  {
    const uint32_t* wp = wh2 + (size_t)dir * 64 * 512;
#pragma unroll
    for (int r = 0; r < 4; r++)
#pragma unroll
      for (int w = 0; w < 16; w++) wq[r][w] = wp[(p * 16 + w) * 512 + j + 128 * r];
  }
#pragma unroll
  for (int r = 0; r < 4; r++)
#pragma unroll
    for (int w = 0; w < 16; w++) asm volatile("" : "+v"(wq[r][w]));

  // per-thread gate constants: lane p==2 computes tanh = 2*sigmoid(2z)-1
  const float kmul = (p == 2) ? (-2.0f * 1.44269504f) : -1.44269504f;
  const float gm = (p == 2) ? 2.0f : 1.0f;
  const float gb = (p == 2) ? -1.0f : 0.0f;

  const uint16_t* xgp = xg + ((size_t)dir * M_TOT + b * T_SEQ) * 512;

  if (tid < 64) hbuf[0][tid] = 0u;
  float c = 0.0f;
  const int t0 = dir ? (T_SEQ - 1) : 0;
  const int t1 = dir ? (T_SEQ - 2) : 1;
  uint16_t xg_c = xgp[(size_t)t0 * 512 + tid];  // step 0
  uint16_t xg_n = xgp[(size_t)t1 * 512 + tid];  // step 1
  __syncthreads();

  for (int s = 0; s < T_SEQ; s++) {
    const int t = dir ? (T_SEQ - 1 - s) : s;
    const int par = s & 1;

    // prefetch step s+2 (2-deep: hides L3/HBM latency across one full step)
    uint16_t xg_n2 = 0;
    if (s + 2 < T_SEQ) {
      const int tn = dir ? (t - 2) : (t + 2);
      xg_n2 = xgp[(size_t)tn * 512 + tid];
    }

    // accumulators seeded with this thread's xg term (row j+128p -> a_p)
    float xgv = (float)__builtin_bit_cast(_Float16, xg_c);
    float a0 = (p == 0) ? xgv : 0.0f;
    float a1 = (p == 1) ? xgv : 0.0f;
    float a2 = (p == 2) ? xgv : 0.0f;
    float a3 = (p == 3) ? xgv : 0.0f;

    // partial dots over h-words [p*16, p*16+16)
    const uint4* ib = (const uint4*)(&hbuf[par][p * 16]);
#pragma unroll
    for (int kk = 0; kk < 4; kk++) {
      uint4 v = ib[kk];
      a0 = dot2(v.x, wq[0][4 * kk + 0], a0);
      a1 = dot2(v.x, wq[1][4 * kk + 0], a1);
      a2 = dot2(v.x, wq[2][4 * kk + 0], a2);
      a3 = dot2(v.x, wq[3][4 * kk + 0], a3);
      a0 = dot2(v.y, wq[0][4 * kk + 1], a0);
      a1 = dot2(v.y, wq[1][4 * kk + 1], a1);
      a2 = dot2(v.y, wq[2][4 * kk + 1], a2);
      a3 = dot2(v.y, wq[3][4 * kk + 1], a3);
      a0 = dot2(v.z, wq[0][4 * kk + 2], a0);
      a1 = dot2(v.z, wq[1][4 * kk + 2], a1);
      a2 = dot2(v.z, wq[2][4 * kk + 2], a2);
      a3 = dot2(v.z, wq[3][4 * kk + 2], a3);
      a0 = dot2(v.w, wq[0][4 * kk + 3], a0);
      a1 = dot2(v.w, wq[1][4 * kk + 3], a1);
      a2 = dot2(v.w, wq[2][4 * kk + 3], a2);
      a3 = dot2(v.w, wq[3][4 * kk + 3], a3);
    }

    // quad transpose-reduce: lane p ends with the FULL sum of gate row j+128p
    float keep1 = (p & 1) ? a1 : a0;
    float send1 = (p & 1) ? a0 : a1;
    float u = keep1 + dppf<0xB1>(send1);
    float keep2 = (p & 1) ? a3 : a2;
    float send2 = (p & 1) ? a2 : a3;
    float v2 = keep2 + dppf<0xB1>(send2);
    float keep3 = (p & 2) ? v2 : u;
    float send3 = (p & 2) ? u : v2;
    float z = keep3 + dppf<0x4E>(send3);

    // one transcendental per lane; tanh via sigmoid identity for p==2
    float e = __builtin_amdgcn_exp2f(z * kmul);
    float sg = __builtin_amdgcn_rcpf(1.0f + e);
    float gv = __builtin_fmaf(sg, gm, gb);

    // quad broadcast: every lane gets i,f,g,o (bitwise identical across quad)
    float gi = dppf<0x00>(gv);
    float gf = dppf<0x55>(gv);
    float gg = dppf<0xAA>(gv);
    float go = dppf<0xFF>(gv);

    c = __builtin_fmaf(gf, c, gi * gg);
    float ec = __builtin_amdgcn_exp2f(c * (-2.0f * 1.44269504f));
    float th = __builtin_fmaf(2.0f, __builtin_amdgcn_rcpf(1.0f + ec), -1.0f);
    float h = go * th;

    if (p == 0) {
      uint16_t hu = __builtin_bit_cast(uint16_t, (_Float16)h);
      ((uint16_t*)(&hbuf[par ^ 1][0]))[j] = hu;
      if (FINAL) {
        fout[(size_t)(b * T_SEQ + t) * 256 + dir * 128 + j] = h;
      } else {
        hout[(size_t)(b * T_SEQ + t) * 256 + dir * 128 + j] = hu;
      }
    }
    xg_c = xg_n;
    xg_n = xg_n2;
    __syncthreads();
  }
}

extern "C" void kernel_launch(void* const* d_in, const int* in_sizes, int n_in,
                              void* d_out, int out_size, void* d_ws, size_t ws_size,
                              hipStream_t stream) {
  const float* x = (const float*)d_in[0];
  const float* Wih_fw1 = (const float*)d_in[2];
  const float* Whh_fw1 = (const float*)d_in[3];
  const float* bih_fw1 = (const float*)d_in[4];
  const float* bhh_fw1 = (const float*)d_in[5];
  const float* Wih_bw1 = (const float*)d_in[6];
  const float* Whh_bw1 = (const float*)d_in[7];
  const float* bih_bw1 = (const float*)d_in[8];
  const float* bhh_bw1 = (const float*)d_in[9];
  const float* Wih_fw2 = (const float*)d_in[10];
  const float* Whh_fw2 = (const float*)d_in[11];
  const float* bih_fw2 = (const float*)d_in[12];
  const float* bhh_fw2 = (const float*)d_in[13];
  const float* Wih_bw2 = (const float*)d_in[14];
  const float* Whh_bw2 = (const float*)d_in[15];
  const float* bih_bw2 = (const float*)d_in[16];
  const float* bhh_bw2 = (const float*)d_in[17];

  uint8_t* ws = (uint8_t*)d_ws;
  // ws layout (bytes):
  //   0        : whbuf   [4 cells][64][512] u32     512 KB
  //   524288   : btbuf1  [2*512][64]  u32           256 KB
  //   786432   : btbuf2  [2*512][128] u32           512 KB
  //   1310720  : biascat [2 layers][1024] f32         8 KB
  //   2097152  : xf16    [M][64] u32                 16 MB
  //   18874368 : out1    [M][128] u32 (f16x2)        32 MB
  //   52428800 : xg      [2][M][512] f16            128 MB
  uint32_t* whbuf = (uint32_t*)(ws + 0);
  uint32_t* btbuf1 = (uint32_t*)(ws + 524288);
  uint32_t* btbuf2 = (uint32_t*)(ws + 786432);
  float* biascat = (float*)(ws + 1310720);
  uint32_t* xf16 = (uint32_t*)(ws + 2097152);
  uint32_t* out1 = (uint32_t*)(ws + 18874368);
  uint16_t* xgbuf = (uint16_t*)(ws + 52428800);
  float* fout = (float*)d_out;

  // --- weight / bias / input packing ---
  prep_whh<<<128, 256, 0, stream>>>(Whh_fw1, whbuf + 0 * 32768);
  prep_whh<<<128, 256, 0, stream>>>(Whh_bw1, whbuf + 1 * 32768);
  prep_whh<<<128, 256, 0, stream>>>(Whh_fw2, whbuf + 2 * 32768);
  prep_whh<<<128, 256, 0, stream>>>(Whh_bw2, whbuf + 3 * 32768);
  prep_bt<64><<<128, 256, 0, stream>>>(Wih_fw1, btbuf1 + 0);
  prep_bt<64><<<128, 256, 0, stream>>>(Wih_bw1, btbuf1 + 512 * 64);
  prep_bt<128><<<256, 256, 0, stream>>>(Wih_fw2, btbuf2 + 0);
  prep_bt<128><<<256, 256, 0, stream>>>(Wih_bw2, btbuf2 + 512 * 128);
  prep_biasc<<<2, 256, 0, stream>>>(bih_fw1, bhh_fw1, biascat + 0);
  prep_biasc<<<2, 256, 0, stream>>>(bih_bw1, bhh_bw1, biascat + 512);
  prep_biasc<<<2, 256, 0, stream>>>(bih_fw2, bhh_fw2, biascat + 1024);
  prep_biasc<<<2, 256, 0, stream>>>(bih_bw2, bhh_bw2, biascat + 1536);
  prep_x<<<(B_SZ * T_SEQ * 64) / 256, 256, 0, stream>>>((const float2*)x, xf16);

  // --- layer 1: xg GEMM + scan ---
  xg_gemm<64><<<dim3(16, 1024), 256, 0, stream>>>(xf16, btbuf1, biascat, xgbuf);
  scan_kernel<false><<<128, 512, 0, stream>>>(xgbuf, whbuf + 0, (uint16_t*)out1, nullptr);

  // --- layer 2: xg GEMM (reads out1) + scan -> d_out ---
  xg_gemm<128><<<dim3(16, 1024), 256, 0, stream>>>(out1, btbuf2, biascat + 1024, xgbuf);
  scan_kernel<true><<<128, 512, 0, stream>>>(xgbuf, whbuf + 2 * 32768, nullptr, fout);
}

// Round 3
// 1520.996 us; speedup vs baseline: 1.1007x; 1.0556x over previous
//
#include <hip/hip_runtime.h>
#include <hip/hip_fp16.h>
#include <stdint.h>

// BiLSTM 2-layer, B=64, T=1024, D=H=128.
// Round 9: round-8 gained only 725->625us. Re-analysis: FETCH_SIZE is HBM
// traffic only -- scratch spill-reloads / remat'd global reloads of whbuf are
// L2-served and FETCH-invisible. VGPR_Count=48 with 64 "resident" weight
// words means the weights are NOT in arch VGPRs: reload path = 128KB/block/
// step = 27 TB/s aggregate L2 = the measured 610ns/step floor. Also the xg
// rotation copy (xg_n = xg_n2, conditional load) forces a per-step waitcnt on
// the just-issued load.
// Fixes:
//  1) Pin weights in AGPRs ("+a" asm, re-asserted each outer iter) -- gfx950
//     unified file, v_dot2 sources AGPRs directly; kills spill AND remat.
//  2) 8-slot unroll-8 prefetch pipeline: step s loads step s+4 into slot
//     (k+4)&7 unconditionally (clamped addr); use of slot k is 4 steps after
//     its load -> counted vmcnt, no copies, no per-step drain.
//  3) xg term added once after the quad reduce (store-side permutation makes
//     xg[..+tid] the lane's own gate row) -- removes 4 cndmask from the chain.

#define T_SEQ 1024
#define B_SZ  64
#define M_TOT 65536  // B*T rows

typedef _Float16 h2_t __attribute__((ext_vector_type(2)));
typedef _Float16 f16x8 __attribute__((ext_vector_type(8)));
typedef float f32x4 __attribute__((ext_vector_type(4)));

__device__ inline float dot2(uint32_t a, uint32_t b, float c) {
  return __builtin_amdgcn_fdot2(__builtin_bit_cast(h2_t, a),
                                __builtin_bit_cast(h2_t, b), c, false);
}

__device__ inline uint32_t pack2(float a, float b) {
  uint16_t ua = __builtin_bit_cast(uint16_t, (_Float16)a);
  uint16_t ub = __builtin_bit_cast(uint16_t, (_Float16)b);
  return (uint32_t)ua | ((uint32_t)ub << 16);
}

// DPP quad_perm helper (compile-time ctrl). xor1=0xB1, xor2=0x4E,
// bcast lane q = q*0x55.
template <int CTRL>
__device__ inline float dppf(float v) {
  return __builtin_bit_cast(
      float, __builtin_amdgcn_update_dpp(0, __builtin_bit_cast(int, v), CTRL,
                                         0xF, 0xF, true));
}

// ---------- prep kernels ----------

// Whh [512][128] f32 -> wh [64 kw][512 g] u32 (f16x2 along k)
__global__ void prep_whh(const float* __restrict__ Whh, uint32_t* __restrict__ dst) {
  int idx = blockIdx.x * 256 + threadIdx.x;  // < 64*512
  int kw = idx >> 9, g = idx & 511;
  dst[idx] = pack2(Whh[g * 128 + 2 * kw], Whh[g * 128 + 2 * kw + 1]);
}

// Wih [512][2*KW] f32 -> Bt [512 g][KW kw] u32 row-major (= B^T rows for MFMA)
template <int KW>
__global__ void prep_bt(const float* __restrict__ Wih, uint32_t* __restrict__ dst) {
  int idx = blockIdx.x * 256 + threadIdx.x;  // < 512*KW
  constexpr int SH = (KW == 64) ? 6 : 7;
  int g = idx >> SH, kw = idx & (KW - 1);
  dst[idx] = pack2(Wih[g * (2 * KW) + 2 * kw], Wih[g * (2 * KW) + 2 * kw + 1]);
}

__global__ void prep_biasc(const float* __restrict__ bih, const float* __restrict__ bhh,
                           float* __restrict__ dst) {
  int idx = blockIdx.x * 256 + threadIdx.x;  // < 512
  if (idx < 512) dst[idx] = bih[idx] + bhh[idx];
}

// x [B,T,128] f32 -> packed f16x2 [M][64] u32
__global__ void prep_x(const float2* __restrict__ x2, uint32_t* __restrict__ xf16) {
  int idx = blockIdx.x * 256 + threadIdx.x;
  float2 v = x2[idx];
  xf16[idx] = pack2(v.x, v.y);
}

// ---------- xg GEMM: xg[cell][m][512] f16 = A[m][:] . Wih_cell^T + bias ----------
// A: [M][KW] u32 (f16x2, row-major). Bt: [1024 n][KW] u32 (n = cell*512+g).
// Grid (16 n-tiles, 1024 m-tiles) x 256 thr. 64x64 tile, 4 waves of 32x32.
// Store-side gate permutation: gp = ((g&127)<<2)|(g>>7) so the scan's quad
// thread map (tid = 4j+p -> gate row j+128p) loads consecutive u16.
template <int KW>
__global__ __launch_bounds__(256) void xg_gemm(
    const uint32_t* __restrict__ A, const uint32_t* __restrict__ Bt,
    const float* __restrict__ biascat, uint16_t* __restrict__ xg) {
  const int n0 = blockIdx.x * 64;
  const int m0 = blockIdx.y * 64;
  const int tid = threadIdx.x;
  __shared__ uint32_t At[64][36];   // stride 36 words: 16B-aligned quads, 2-way banks
  __shared__ uint32_t Bts[64][36];
  const int lr = tid >> 2, lq = tid & 3;
  const int wave = tid >> 6, lane = tid & 63;
  const int wm = wave >> 1, wn = wave & 1;
  const int q = lane >> 4, ln16 = lane & 15;
  f32x4 acc[2][2] = {};
  for (int kb = 0; kb < KW; kb += 16) {
    uint4 av = *(const uint4*)&A[(size_t)(m0 + lr) * KW + kb + lq * 4];
    uint4 bv = *(const uint4*)&Bt[(size_t)(n0 + lr) * KW + kb + lq * 4];
    __syncthreads();  // previous iteration's fragment reads complete
    *(uint4*)&At[lr][lq * 4] = av;
    *(uint4*)&Bts[lr][lq * 4] = bv;
    __syncthreads();
#pragma unroll
    for (int mi = 0; mi < 2; mi++) {
      f16x8 af = *(const f16x8*)&At[wm * 32 + mi * 16 + ln16][q * 4];
#pragma unroll
      for (int ni = 0; ni < 2; ni++) {
        f16x8 bf = *(const f16x8*)&Bts[wn * 32 + ni * 16 + ln16][q * 4];
        acc[mi][ni] = __builtin_amdgcn_mfma_f32_16x16x32_f16(af, bf, acc[mi][ni], 0, 0, 0);
      }
    }
  }
  // D layout (verified m89/m91): col = lane&15, row = (lane>>4)*4 + reg
#pragma unroll
  for (int mi = 0; mi < 2; mi++)
#pragma unroll
    for (int ni = 0; ni < 2; ni++) {
      int n = n0 + wn * 32 + ni * 16 + ln16;
      int cell = n >> 9, g = n & 511;
      int gp = ((g & 127) << 2) | (g >> 7);  // quad-interleaved gate index
      float bs = biascat[n];
#pragma unroll
      for (int i = 0; i < 4; i++) {
        int m = m0 + wm * 32 + mi * 16 + q * 4 + i;
        float v = acc[mi][ni][i] + bs;
        xg[((size_t)cell * M_TOT + m) * 512 + gp] =
            __builtin_bit_cast(uint16_t, (_Float16)v);
      }
    }
}

// ---------- scan: gates_t = xg_t + Whh.h_{t-1} ----------
// 128 WGs (dir*64+b) x 512 thr. Thread (j = tid>>2, p = tid&3) accumulates
// gate rows {j+128r | r=0..3} over h-words [p*16, p*16+16). Quad transpose-
// reduce leaves lane p with the full sum of its OWN gate (row j+128p); one
// exp+rcp per lane; 4 DPP broadcasts; redundant-but-identical cell update.
// One barrier per step; weights AGPR-pinned; 8-slot xg prefetch pipeline.
template <bool FINAL>
__global__ __launch_bounds__(512, 2) void scan_kernel(
    const uint16_t* __restrict__ xg, const uint32_t* __restrict__ wh2,
    uint16_t* __restrict__ hout, float* __restrict__ fout) {
  const int tid = threadIdx.x;
  const int j = tid >> 2;  // hidden unit 0..127
  const int p = tid & 3;   // quarter-K span / gate selector
  const int b = blockIdx.x & 63;
  const int dir = blockIdx.x >> 6;

  __shared__ __align__(16) uint32_t hbuf[2][64];  // [parity][h f16x2]

  // Whh slice: rows {j+128r}, k-words [p*16, p*16+16) = 64 u32 -> AGPRs.
  uint32_t wq[4][16];
  {
    const uint32_t* wp = wh2 + (size_t)dir * 64 * 512;
#pragma unroll
    for (int r = 0; r < 4; r++)
#pragma unroll
      for (int w = 0; w < 16; w++) wq[r][w] = wp[(p * 16 + w) * 512 + j + 128 * r];
  }
#pragma unroll
  for (int r = 0; r < 4; r++)
#pragma unroll
    for (int w = 0; w < 16; w++) asm volatile("" : "+a"(wq[r][w]));

  // per-thread gate constants: lane p==2 computes tanh = 2*sigmoid(2z)-1
  const float kmul = (p == 2) ? (-2.0f * 1.44269504f) : -1.44269504f;
  const float gm = (p == 2) ? 2.0f : 1.0f;
  const float gb = (p == 2) ? -1.0f : 0.0f;

  const uint16_t* xgp = xg + ((size_t)dir * M_TOT + b * T_SEQ) * 512 + tid;

  if (tid < 64) hbuf[0][tid] = 0u;
  float c = 0.0f;

  // 8-slot prefetch pipeline: slot(s) = s&7; prologue fills steps 0..3.
  uint16_t xr[8];
#pragma unroll
  for (int k = 0; k < 4; k++) {
    const int tk = dir ? (T_SEQ - 1 - k) : k;
    xr[k] = xgp[(size_t)tk * 512];
  }
  __syncthreads();

  for (int s0 = 0; s0 < T_SEQ; s0 += 8) {
    // re-pin weights each outer iter: forbids spill/remat of the AGPR home
#pragma unroll
    for (int r = 0; r < 4; r++)
#pragma unroll
      for (int w = 0; w < 16; w++) asm volatile("" : "+a"(wq[r][w]));
#pragma unroll
    for (int k = 0; k < 8; k++) {
      const int s = s0 + k;
      const int par = k & 1;

      // issue prefetch for step s+4 into slot (k+4)&7 (unconditional, clamped)
      {
        int sn = s + 4;
        sn = (sn < T_SEQ) ? sn : (T_SEQ - 1);
        const int tn = dir ? (T_SEQ - 1 - sn) : sn;
        xr[(k + 4) & 7] = xgp[(size_t)tn * 512];
      }

      // partial dots over h-words [p*16, p*16+16)
      float a0 = 0.f, a1 = 0.f, a2 = 0.f, a3 = 0.f;
      const uint4* ib = (const uint4*)(&hbuf[par][p * 16]);
#pragma unroll
      for (int kk = 0; kk < 4; kk++) {
        uint4 v = ib[kk];
        a0 = dot2(v.x, wq[0][4 * kk + 0], a0);
        a1 = dot2(v.x, wq[1][4 * kk + 0], a1);
        a2 = dot2(v.x, wq[2][4 * kk + 0], a2);
        a3 = dot2(v.x, wq[3][4 * kk + 0], a3);
        a0 = dot2(v.y, wq[0][4 * kk + 1], a0);
        a1 = dot2(v.y, wq[1][4 * kk + 1], a1);
        a2 = dot2(v.y, wq[2][4 * kk + 1], a2);
        a3 = dot2(v.y, wq[3][4 * kk + 1], a3);
        a0 = dot2(v.z, wq[0][4 * kk + 2], a0);
        a1 = dot2(v.z, wq[1][4 * kk + 2], a1);
        a2 = dot2(v.z, wq[2][4 * kk + 2], a2);
        a3 = dot2(v.z, wq[3][4 * kk + 2], a3);
        a0 = dot2(v.w, wq[0][4 * kk + 3], a0);
        a1 = dot2(v.w, wq[1][4 * kk + 3], a1);
        a2 = dot2(v.w, wq[2][4 * kk + 3], a2);
        a3 = dot2(v.w, wq[3][4 * kk + 3], a3);
      }

      // quad transpose-reduce: lane p ends with full sum of gate row j+128p
      float keep1 = (p & 1) ? a1 : a0;
      float send1 = (p & 1) ? a0 : a1;
      float u = keep1 + dppf<0xB1>(send1);
      float keep2 = (p & 1) ? a3 : a2;
      float send2 = (p & 1) ? a2 : a3;
      float v2 = keep2 + dppf<0xB1>(send2);
      float keep3 = (p & 2) ? v2 : u;
      float send3 = (p & 2) ? u : v2;
      float z = keep3 + dppf<0x4E>(send3);

      // fold in this lane's own xg term (vmcnt wait lands here, after dots)
      z += (float)__builtin_bit_cast(_Float16, xr[k]);

      // one transcendental per lane; tanh via sigmoid identity for p==2
      float e = __builtin_amdgcn_exp2f(z * kmul);
      float sg = __builtin_amdgcn_rcpf(1.0f + e);
      float gv = __builtin_fmaf(sg, gm, gb);

      // quad broadcast: every lane gets i,f,g,o (bitwise identical in quad)
      float gi = dppf<0x00>(gv);
      float gf = dppf<0x55>(gv);
      float gg = dppf<0xAA>(gv);
      float go = dppf<0xFF>(gv);

      c = __builtin_fmaf(gf, c, gi * gg);
      float ec = __builtin_amdgcn_exp2f(c * (-2.0f * 1.44269504f));
      float th = __builtin_fmaf(2.0f, __builtin_amdgcn_rcpf(1.0f + ec), -1.0f);
      float h = go * th;

      if (p == 0) {
        const int t = dir ? (T_SEQ - 1 - s) : s;
        uint16_t hu = __builtin_bit_cast(uint16_t, (_Float16)h);
        ((uint16_t*)(&hbuf[par ^ 1][0]))[j] = hu;
        if (FINAL) {
          fout[(size_t)(b * T_SEQ + t) * 256 + dir * 128 + j] = h;
        } else {
          hout[(size_t)(b * T_SEQ + t) * 256 + dir * 128 + j] = hu;
        }
      }
      __syncthreads();
    }
  }
}

extern "C" void kernel_launch(void* const* d_in, const int* in_sizes, int n_in,
                              void* d_out, int out_size, void* d_ws, size_t ws_size,
                              hipStream_t stream) {
  const float* x = (const float*)d_in[0];
  const float* Wih_fw1 = (const float*)d_in[2];
  const float* Whh_fw1 = (const float*)d_in[3];
  const float* bih_fw1 = (const float*)d_in[4];
  const float* bhh_fw1 = (const float*)d_in[5];
  const float* Wih_bw1 = (const float*)d_in[6];
  const float* Whh_bw1 = (const float*)d_in[7];
  const float* bih_bw1 = (const float*)d_in[8];
  const float* bhh_bw1 = (const float*)d_in[9];
  const float* Wih_fw2 = (const float*)d_in[10];
  const float* Whh_fw2 = (const float*)d_in[11];
  const float* bih_fw2 = (const float*)d_in[12];
  const float* bhh_fw2 = (const float*)d_in[13];
  const float* Wih_bw2 = (const float*)d_in[14];
  const float* Whh_bw2 = (const float*)d_in[15];
  const float* bih_bw2 = (const float*)d_in[16];
  const float* bhh_bw2 = (const float*)d_in[17];

  uint8_t* ws = (uint8_t*)d_ws;
  // ws layout (bytes):
  //   0        : whbuf   [4 cells][64][512] u32     512 KB
  //   524288   : btbuf1  [2*512][64]  u32           256 KB
  //   786432   : btbuf2  [2*512][128] u32           512 KB
  //   1310720  : biascat [2 layers][1024] f32         8 KB
  //   2097152  : xf16    [M][64] u32                 16 MB
  //   18874368 : out1    [M][128] u32 (f16x2)        32 MB
  //   52428800 : xg      [2][M][512] f16            128 MB
  uint32_t* whbuf = (uint32_t*)(ws + 0);
  uint32_t* btbuf1 = (uint32_t*)(ws + 524288);
  uint32_t* btbuf2 = (uint32_t*)(ws + 786432);
  float* biascat = (float*)(ws + 1310720);
  uint32_t* xf16 = (uint32_t*)(ws + 2097152);
  uint32_t* out1 = (uint32_t*)(ws + 18874368);
  uint16_t* xgbuf = (uint16_t*)(ws + 52428800);
  float* fout = (float*)d_out;

  // --- weight / bias / input packing ---
  prep_whh<<<128, 256, 0, stream>>>(Whh_fw1, whbuf + 0 * 32768);
  prep_whh<<<128, 256, 0, stream>>>(Whh_bw1, whbuf + 1 * 32768);
  prep_whh<<<128, 256, 0, stream>>>(Whh_fw2, whbuf + 2 * 32768);
  prep_whh<<<128, 256, 0, stream>>>(Whh_bw2, whbuf + 3 * 32768);
  prep_bt<64><<<128, 256, 0, stream>>>(Wih_fw1, btbuf1 + 0);
  prep_bt<64><<<128, 256, 0, stream>>>(Wih_bw1, btbuf1 + 512 * 64);
  prep_bt<128><<<256, 256, 0, stream>>>(Wih_fw2, btbuf2 + 0);
  prep_bt<128><<<256, 256, 0, stream>>>(Wih_bw2, btbuf2 + 512 * 128);
  prep_biasc<<<2, 256, 0, stream>>>(bih_fw1, bhh_fw1, biascat + 0);
  prep_biasc<<<2, 256, 0, stream>>>(bih_bw1, bhh_bw1, biascat + 512);
  prep_biasc<<<2, 256, 0, stream>>>(bih_fw2, bhh_fw2, biascat + 1024);
  prep_biasc<<<2, 256, 0, stream>>>(bih_bw2, bhh_bw2, biascat + 1536);
  prep_x<<<(B_SZ * T_SEQ * 64) / 256, 256, 0, stream>>>((const float2*)x, xf16);

  // --- layer 1: xg GEMM + scan ---
  xg_gemm<64><<<dim3(16, 1024), 256, 0, stream>>>(xf16, btbuf1, biascat, xgbuf);
  scan_kernel<false><<<128, 512, 0, stream>>>(xgbuf, whbuf + 0, (uint16_t*)out1, nullptr);

  // --- layer 2: xg GEMM (reads out1) + scan -> d_out ---
  xg_gemm<128><<<dim3(16, 1024), 256, 0, stream>>>(out1, btbuf2, biascat + 1024, xgbuf);
  scan_kernel<true><<<128, 512, 0, stream>>>(xgbuf, whbuf + 2 * 32768, nullptr, fout);
}

// Round 4
// 1501.453 us; speedup vs baseline: 1.1150x; 1.0130x over previous
//
#include <hip/hip_runtime.h>
#include <hip/hip_fp16.h>
#include <stdint.h>

// BiLSTM 2-layer, B=64, T=1024, D=H=128.
// Round 10: round-9's AGPR pinning made weights arch-resident (VGPR 48->84)
// but gained only 36us -> the L2-weight-reload theory was WRONG; weights were
// always effectively resident. The real per-step cost: __syncthreads()
// lowers to s_waitcnt vmcnt(0) lgkmcnt(0) + s_barrier, so EVERY step drains
// the just-issued xg prefetch (L3-resident 64MB stream, ~400-600cy) and the
// h/out store retire before crossing the barrier. The 8-slot prefetch
// pipeline was structurally defeated (guide §5: the barrier drain is THE
// known stall; fix is counted vmcnt across raw s_barrier -- T4).
// Fix: per-step barrier becomes
//     s_waitcnt lgkmcnt(0)   (orders LDS h-write, the only cross-wave dep)
//     s_barrier              (raw, no vmcnt drain)
//     ""::: "memory"         (fence: nothing hoists above the barrier)
// Loads/stores now stay in flight across steps; compiler emits counted
// vmcnt(N) at each xr[k] use (4 steps of slack).

#define T_SEQ 1024
#define B_SZ  64
#define M_TOT 65536  // B*T rows

typedef _Float16 h2_t __attribute__((ext_vector_type(2)));
typedef _Float16 f16x8 __attribute__((ext_vector_type(8)));
typedef float f32x4 __attribute__((ext_vector_type(4)));

__device__ inline float dot2(uint32_t a, uint32_t b, float c) {
  return __builtin_amdgcn_fdot2(__builtin_bit_cast(h2_t, a),
                                __builtin_bit_cast(h2_t, b), c, false);
}

__device__ inline uint32_t pack2(float a, float b) {
  uint16_t ua = __builtin_bit_cast(uint16_t, (_Float16)a);
  uint16_t ub = __builtin_bit_cast(uint16_t, (_Float16)b);
  return (uint32_t)ua | ((uint32_t)ub << 16);
}

// DPP quad_perm helper (compile-time ctrl). xor1=0xB1, xor2=0x4E,
// bcast lane q = q*0x55.
template <int CTRL>
__device__ inline float dppf(float v) {
  return __builtin_bit_cast(
      float, __builtin_amdgcn_update_dpp(0, __builtin_bit_cast(int, v), CTRL,
                                         0xF, 0xF, true));
}

// ---------- prep kernels ----------

// Whh [512][128] f32 -> wh [64 kw][512 g] u32 (f16x2 along k)
__global__ void prep_whh(const float* __restrict__ Whh, uint32_t* __restrict__ dst) {
  int idx = blockIdx.x * 256 + threadIdx.x;  // < 64*512
  int kw = idx >> 9, g = idx & 511;
  dst[idx] = pack2(Whh[g * 128 + 2 * kw], Whh[g * 128 + 2 * kw + 1]);
}

// Wih [512][2*KW] f32 -> Bt [512 g][KW kw] u32 row-major (= B^T rows for MFMA)
template <int KW>
__global__ void prep_bt(const float* __restrict__ Wih, uint32_t* __restrict__ dst) {
  int idx = blockIdx.x * 256 + threadIdx.x;  // < 512*KW
  constexpr int SH = (KW == 64) ? 6 : 7;
  int g = idx >> SH, kw = idx & (KW - 1);
  dst[idx] = pack2(Wih[g * (2 * KW) + 2 * kw], Wih[g * (2 * KW) + 2 * kw + 1]);
}

__global__ void prep_biasc(const float* __restrict__ bih, const float* __restrict__ bhh,
                           float* __restrict__ dst) {
  int idx = blockIdx.x * 256 + threadIdx.x;  // < 512
  if (idx < 512) dst[idx] = bih[idx] + bhh[idx];
}

// x [B,T,128] f32 -> packed f16x2 [M][64] u32
__global__ void prep_x(const float2* __restrict__ x2, uint32_t* __restrict__ xf16) {
  int idx = blockIdx.x * 256 + threadIdx.x;
  float2 v = x2[idx];
  xf16[idx] = pack2(v.x, v.y);
}

// ---------- xg GEMM: xg[cell][m][512] f16 = A[m][:] . Wih_cell^T + bias ----------
// A: [M][KW] u32 (f16x2, row-major). Bt: [1024 n][KW] u32 (n = cell*512+g).
// Grid (16 n-tiles, 1024 m-tiles) x 256 thr. 64x64 tile, 4 waves of 32x32.
// Store-side gate permutation: gp = ((g&127)<<2)|(g>>7) so the scan's quad
// thread map (tid = 4j+p -> gate row j+128p) loads consecutive u16.
template <int KW>
__global__ __launch_bounds__(256) void xg_gemm(
    const uint32_t* __restrict__ A, const uint32_t* __restrict__ Bt,
    const float* __restrict__ biascat, uint16_t* __restrict__ xg) {
  const int n0 = blockIdx.x * 64;
  const int m0 = blockIdx.y * 64;
  const int tid = threadIdx.x;
  __shared__ uint32_t At[64][36];   // stride 36 words: 16B-aligned quads, 2-way banks
  __shared__ uint32_t Bts[64][36];
  const int lr = tid >> 2, lq = tid & 3;
  const int wave = tid >> 6, lane = tid & 63;
  const int wm = wave >> 1, wn = wave & 1;
  const int q = lane >> 4, ln16 = lane & 15;
  f32x4 acc[2][2] = {};
  for (int kb = 0; kb < KW; kb += 16) {
    uint4 av = *(const uint4*)&A[(size_t)(m0 + lr) * KW + kb + lq * 4];
    uint4 bv = *(const uint4*)&Bt[(size_t)(n0 + lr) * KW + kb + lq * 4];
    __syncthreads();  // previous iteration's fragment reads complete
    *(uint4*)&At[lr][lq * 4] = av;
    *(uint4*)&Bts[lr][lq * 4] = bv;
    __syncthreads();
#pragma unroll
    for (int mi = 0; mi < 2; mi++) {
      f16x8 af = *(const f16x8*)&At[wm * 32 + mi * 16 + ln16][q * 4];
#pragma unroll
      for (int ni = 0; ni < 2; ni++) {
        f16x8 bf = *(const f16x8*)&Bts[wn * 32 + ni * 16 + ln16][q * 4];
        acc[mi][ni] = __builtin_amdgcn_mfma_f32_16x16x32_f16(af, bf, acc[mi][ni], 0, 0, 0);
      }
    }
  }
  // D layout (verified m89/m91): col = lane&15, row = (lane>>4)*4 + reg
#pragma unroll
  for (int mi = 0; mi < 2; mi++)
#pragma unroll
    for (int ni = 0; ni < 2; ni++) {
      int n = n0 + wn * 32 + ni * 16 + ln16;
      int cell = n >> 9, g = n & 511;
      int gp = ((g & 127) << 2) | (g >> 7);  // quad-interleaved gate index
      float bs = biascat[n];
#pragma unroll
      for (int i = 0; i < 4; i++) {
        int m = m0 + wm * 32 + mi * 16 + q * 4 + i;
        float v = acc[mi][ni][i] + bs;
        xg[((size_t)cell * M_TOT + m) * 512 + gp] =
            __builtin_bit_cast(uint16_t, (_Float16)v);
      }
    }
}

// ---------- scan: gates_t = xg_t + Whh.h_{t-1} ----------
// 128 WGs (dir*64+b) x 512 thr. Thread (j = tid>>2, p = tid&3) accumulates
// gate rows {j+128r | r=0..3} over h-words [p*16, p*16+16). Quad transpose-
// reduce leaves lane p with the full sum of its OWN gate (row j+128p); one
// exp+rcp per lane; 4 DPP broadcasts; redundant-but-identical cell update.
// One RAW barrier per step (counted vmcnt across it); weights AGPR-pinned;
// 8-slot xg prefetch pipeline (4 steps of slack).
template <bool FINAL>
__global__ __launch_bounds__(512, 2) void scan_kernel(
    const uint16_t* __restrict__ xg, const uint32_t* __restrict__ wh2,
    uint16_t* __restrict__ hout, float* __restrict__ fout) {
  const int tid = threadIdx.x;
  const int j = tid >> 2;  // hidden unit 0..127
  const int p = tid & 3;   // quarter-K span / gate selector
  const int b = blockIdx.x & 63;
  const int dir = blockIdx.x >> 6;

  __shared__ __align__(16) uint32_t hbuf[2][64];  // [parity][h f16x2]

  // Whh slice: rows {j+128r}, k-words [p*16, p*16+16) = 64 u32 -> AGPRs.
  uint32_t wq[4][16];
  {
    const uint32_t* wp = wh2 + (size_t)dir * 64 * 512;
#pragma unroll
    for (int r = 0; r < 4; r++)
#pragma unroll
      for (int w = 0; w < 16; w++) wq[r][w] = wp[(p * 16 + w) * 512 + j + 128 * r];
  }
#pragma unroll
  for (int r = 0; r < 4; r++)
#pragma unroll
    for (int w = 0; w < 16; w++) asm volatile("" : "+a"(wq[r][w]));

  // per-thread gate constants: lane p==2 computes tanh = 2*sigmoid(2z)-1
  const float kmul = (p == 2) ? (-2.0f * 1.44269504f) : -1.44269504f;
  const float gm = (p == 2) ? 2.0f : 1.0f;
  const float gb = (p == 2) ? -1.0f : 0.0f;

  const uint16_t* xgp = xg + ((size_t)dir * M_TOT + b * T_SEQ) * 512 + tid;

  if (tid < 64) hbuf[0][tid] = 0u;
  float c = 0.0f;

  // 8-slot prefetch pipeline: slot(s) = s&7; prologue fills steps 0..3.
  uint16_t xr[8];
#pragma unroll
  for (int k = 0; k < 4; k++) {
    const int tk = dir ? (T_SEQ - 1 - k) : k;
    xr[k] = xgp[(size_t)tk * 512];
  }
  __syncthreads();  // prologue: full drain once is fine

  for (int s0 = 0; s0 < T_SEQ; s0 += 8) {
    // re-pin weights each outer iter: forbids spill/remat of the AGPR home
#pragma unroll
    for (int r = 0; r < 4; r++)
#pragma unroll
      for (int w = 0; w < 16; w++) asm volatile("" : "+a"(wq[r][w]));
#pragma unroll
    for (int k = 0; k < 8; k++) {
      const int s = s0 + k;
      const int par = k & 1;

      // issue prefetch for step s+4 into slot (k+4)&7 (unconditional, clamped)
      {
        int sn = s + 4;
        sn = (sn < T_SEQ) ? sn : (T_SEQ - 1);
        const int tn = dir ? (T_SEQ - 1 - sn) : sn;
        xr[(k + 4) & 7] = xgp[(size_t)tn * 512];
      }

      // partial dots over h-words [p*16, p*16+16)
      float a0 = 0.f, a1 = 0.f, a2 = 0.f, a3 = 0.f;
      const uint4* ib = (const uint4*)(&hbuf[par][p * 16]);
#pragma unroll
      for (int kk = 0; kk < 4; kk++) {
        uint4 v = ib[kk];
        a0 = dot2(v.x, wq[0][4 * kk + 0], a0);
        a1 = dot2(v.x, wq[1][4 * kk + 0], a1);
        a2 = dot2(v.x, wq[2][4 * kk + 0], a2);
        a3 = dot2(v.x, wq[3][4 * kk + 0], a3);
        a0 = dot2(v.y, wq[0][4 * kk + 1], a0);
        a1 = dot2(v.y, wq[1][4 * kk + 1], a1);
        a2 = dot2(v.y, wq[2][4 * kk + 1], a2);
        a3 = dot2(v.y, wq[3][4 * kk + 1], a3);
        a0 = dot2(v.z, wq[0][4 * kk + 2], a0);
        a1 = dot2(v.z, wq[1][4 * kk + 2], a1);
        a2 = dot2(v.z, wq[2][4 * kk + 2], a2);
        a3 = dot2(v.z, wq[3][4 * kk + 2], a3);
        a0 = dot2(v.w, wq[0][4 * kk + 3], a0);
        a1 = dot2(v.w, wq[1][4 * kk + 3], a1);
        a2 = dot2(v.w, wq[2][4 * kk + 3], a2);
        a3 = dot2(v.w, wq[3][4 * kk + 3], a3);
      }

      // quad transpose-reduce: lane p ends with full sum of gate row j+128p
      float keep1 = (p & 1) ? a1 : a0;
      float send1 = (p & 1) ? a0 : a1;
      float u = keep1 + dppf<0xB1>(send1);
      float keep2 = (p & 1) ? a3 : a2;
      float send2 = (p & 1) ? a2 : a3;
      float v2 = keep2 + dppf<0xB1>(send2);
      float keep3 = (p & 2) ? v2 : u;
      float send3 = (p & 2) ? u : v2;
      float z = keep3 + dppf<0x4E>(send3);

      // fold in this lane's own xg term (counted vmcnt lands here, after dots)
      z += (float)__builtin_bit_cast(_Float16, xr[k]);

      // one transcendental per lane; tanh via sigmoid identity for p==2
      float e = __builtin_amdgcn_exp2f(z * kmul);
      float sg = __builtin_amdgcn_rcpf(1.0f + e);
      float gv = __builtin_fmaf(sg, gm, gb);

      // quad broadcast: every lane gets i,f,g,o (bitwise identical in quad)
      float gi = dppf<0x00>(gv);
      float gf = dppf<0x55>(gv);
      float gg = dppf<0xAA>(gv);
      float go = dppf<0xFF>(gv);

      c = __builtin_fmaf(gf, c, gi * gg);
      float ec = __builtin_amdgcn_exp2f(c * (-2.0f * 1.44269504f));
      float th = __builtin_fmaf(2.0f, __builtin_amdgcn_rcpf(1.0f + ec), -1.0f);
      float h = go * th;

      if (p == 0) {
        const int t = dir ? (T_SEQ - 1 - s) : s;
        uint16_t hu = __builtin_bit_cast(uint16_t, (_Float16)h);
        ((uint16_t*)(&hbuf[par ^ 1][0]))[j] = hu;
        if (FINAL) {
          fout[(size_t)(b * T_SEQ + t) * 256 + dir * 128 + j] = h;
        } else {
          hout[(size_t)(b * T_SEQ + t) * 256 + dir * 128 + j] = hu;
        }
      }
      // RAW barrier: order ONLY the LDS h-write (lgkmcnt), leave the global
      // prefetch loads / output stores in flight (counted vmcnt at use).
      asm volatile("s_waitcnt lgkmcnt(0)" ::: "memory");
      __builtin_amdgcn_s_barrier();
      asm volatile("" ::: "memory");  // nothing hoists above the barrier
    }
  }
}

extern "C" void kernel_launch(void* const* d_in, const int* in_sizes, int n_in,
                              void* d_out, int out_size, void* d_ws, size_t ws_size,
                              hipStream_t stream) {
  const float* x = (const float*)d_in[0];
  const float* Wih_fw1 = (const float*)d_in[2];
  const float* Whh_fw1 = (const float*)d_in[3];
  const float* bih_fw1 = (const float*)d_in[4];
  const float* bhh_fw1 = (const float*)d_in[5];
  const float* Wih_bw1 = (const float*)d_in[6];
  const float* Whh_bw1 = (const float*)d_in[7];
  const float* bih_bw1 = (const float*)d_in[8];
  const float* bhh_bw1 = (const float*)d_in[9];
  const float* Wih_fw2 = (const float*)d_in[10];
  const float* Whh_fw2 = (const float*)d_in[11];
  const float* bih_fw2 = (const float*)d_in[12];
  const float* bhh_fw2 = (const float*)d_in[13];
  const float* Wih_bw2 = (const float*)d_in[14];
  const float* Whh_bw2 = (const float*)d_in[15];
  const float* bih_bw2 = (const float*)d_in[16];
  const float* bhh_bw2 = (const float*)d_in[17];

  uint8_t* ws = (uint8_t*)d_ws;
  // ws layout (bytes):
  //   0        : whbuf   [4 cells][64][512] u32     512 KB
  //   524288   : btbuf1  [2*512][64]  u32           256 KB
  //   786432   : btbuf2  [2*512][128] u32           512 KB
  //   1310720  : biascat [2 layers][1024] f32         8 KB
  //   2097152  : xf16    [M][64] u32                 16 MB
  //   18874368 : out1    [M][128] u32 (f16x2)        32 MB
  //   52428800 : xg      [2][M][512] f16            128 MB
  uint32_t* whbuf = (uint32_t*)(ws + 0);
  uint32_t* btbuf1 = (uint32_t*)(ws + 524288);
  uint32_t* btbuf2 = (uint32_t*)(ws + 786432);
  float* biascat = (float*)(ws + 1310720);
  uint32_t* xf16 = (uint32_t*)(ws + 2097152);
  uint32_t* out1 = (uint32_t*)(ws + 18874368);
  uint16_t* xgbuf = (uint16_t*)(ws + 52428800);
  float* fout = (float*)d_out;

  // --- weight / bias / input packing ---
  prep_whh<<<128, 256, 0, stream>>>(Whh_fw1, whbuf + 0 * 32768);
  prep_whh<<<128, 256, 0, stream>>>(Whh_bw1, whbuf + 1 * 32768);
  prep_whh<<<128, 256, 0, stream>>>(Whh_fw2, whbuf + 2 * 32768);
  prep_whh<<<128, 256, 0, stream>>>(Whh_bw2, whbuf + 3 * 32768);
  prep_bt<64><<<128, 256, 0, stream>>>(Wih_fw1, btbuf1 + 0);
  prep_bt<64><<<128, 256, 0, stream>>>(Wih_bw1, btbuf1 + 512 * 64);
  prep_bt<128><<<256, 256, 0, stream>>>(Wih_fw2, btbuf2 + 0);
  prep_bt<128><<<256, 256, 0, stream>>>(Wih_bw2, btbuf2 + 512 * 128);
  prep_biasc<<<2, 256, 0, stream>>>(bih_fw1, bhh_fw1, biascat + 0);
  prep_biasc<<<2, 256, 0, stream>>>(bih_bw1, bhh_bw1, biascat + 512);
  prep_biasc<<<2, 256, 0, stream>>>(bih_fw2, bhh_fw2, biascat + 1024);
  prep_biasc<<<2, 256, 0, stream>>>(bih_bw2, bhh_bw2, biascat + 1536);
  prep_x<<<(B_SZ * T_SEQ * 64) / 256, 256, 0, stream>>>((const float2*)x, xf16);

  // --- layer 1: xg GEMM + scan ---
  xg_gemm<64><<<dim3(16, 1024), 256, 0, stream>>>(xf16, btbuf1, biascat, xgbuf);
  scan_kernel<false><<<128, 512, 0, stream>>>(xgbuf, whbuf + 0, (uint16_t*)out1, nullptr);

  // --- layer 2: xg GEMM (reads out1) + scan -> d_out ---
  xg_gemm<128><<<dim3(16, 1024), 256, 0, stream>>>(out1, btbuf2, biascat + 1024, xgbuf);
  scan_kernel<true><<<128, 512, 0, stream>>>(xgbuf, whbuf + 2 * 32768, nullptr, fout);
}

// Round 5
// 1303.618 us; speedup vs baseline: 1.2843x; 1.1518x over previous
//
#include <hip/hip_runtime.h>
#include <hip/hip_fp16.h>
#include <stdint.h>

// BiLSTM 2-layer, B=64, T=1024, D=H=128.
// Round 11: rounds 8-10 falsified all latency theories (barrier drain,
// weight refetch, vmcnt drain): scan stuck at ~584us with chip VALUBusy 35%
// on 128/256 active CUs = ~70% VALU-issue busy on active CUs -> ISSUE-bound.
// The 64 v_dot2/thread/step MACs are the budget. Fix: move the matvec to the
// idle matrix pipe (MfmaUtil was 0.0).
//   gates(512) = Whh(512x128) . h(128) per step as 16 MFMA 16x16x32_f16/wave:
//   - A-fragment built from h with ALL 16 ROWS IDENTICAL (each 16-lane group
//     reads the same h slice from LDS) -> every C row equals the matvec, so
//     lane l holds z[gate 64w+16(l>>4)+(l&15)] = gate 64w+l in acc[l>>4][0].
//     The M-redundancy does the cross-lane broadcast for free: 3 cndmask.
//   - Weights as B-fragments: wb[nt][kt] f16x8, 64 VGPRs, "+v"-pinned.
//     whB layout [gp][kw] with gp=4j+p so the quad tail code is unchanged.
//   - Tail (xg fold, 1 transcendental/lane, quad DPP bcast, redundant cell
//     update, h LDS write, raw lgkm-only barrier) identical to round 8-10.

#define T_SEQ 1024
#define B_SZ  64
#define M_TOT 65536  // B*T rows

typedef _Float16 h2_t __attribute__((ext_vector_type(2)));
typedef _Float16 f16x8 __attribute__((ext_vector_type(8)));
typedef float f32x4 __attribute__((ext_vector_type(4)));

__device__ inline uint32_t pack2(float a, float b) {
  uint16_t ua = __builtin_bit_cast(uint16_t, (_Float16)a);
  uint16_t ub = __builtin_bit_cast(uint16_t, (_Float16)b);
  return (uint32_t)ua | ((uint32_t)ub << 16);
}

// DPP quad_perm helper (compile-time ctrl). xor1=0xB1, xor2=0x4E,
// bcast lane q = q*0x55.
template <int CTRL>
__device__ inline float dppf(float v) {
  return __builtin_bit_cast(
      float, __builtin_amdgcn_update_dpp(0, __builtin_bit_cast(int, v), CTRL,
                                         0xF, 0xF, true));
}

// ---------- prep kernels ----------

// Whh [512][128] f32 -> whB [512 gp][64 kw] u32 (f16x2 along k), gp = 4j+p
__global__ void prep_whB(const float* __restrict__ Whh, uint32_t* __restrict__ dst) {
  int idx = blockIdx.x * 256 + threadIdx.x;  // < 512*64
  int gp = idx >> 6, kw = idx & 63;
  int g = ((gp & 3) << 7) | (gp >> 2);  // gate-major -> original row index
  dst[idx] = pack2(Whh[g * 128 + 2 * kw], Whh[g * 128 + 2 * kw + 1]);
}

// Wih [512][2*KW] f32 -> Bt [512 g][KW kw] u32 row-major (= B^T rows for MFMA)
template <int KW>
__global__ void prep_bt(const float* __restrict__ Wih, uint32_t* __restrict__ dst) {
  int idx = blockIdx.x * 256 + threadIdx.x;  // < 512*KW
  constexpr int SH = (KW == 64) ? 6 : 7;
  int g = idx >> SH, kw = idx & (KW - 1);
  dst[idx] = pack2(Wih[g * (2 * KW) + 2 * kw], Wih[g * (2 * KW) + 2 * kw + 1]);
}

__global__ void prep_biasc(const float* __restrict__ bih, const float* __restrict__ bhh,
                           float* __restrict__ dst) {
  int idx = blockIdx.x * 256 + threadIdx.x;  // < 512
  if (idx < 512) dst[idx] = bih[idx] + bhh[idx];
}

// x [B,T,128] f32 -> packed f16x2 [M][64] u32
__global__ void prep_x(const float2* __restrict__ x2, uint32_t* __restrict__ xf16) {
  int idx = blockIdx.x * 256 + threadIdx.x;
  float2 v = x2[idx];
  xf16[idx] = pack2(v.x, v.y);
}

// ---------- xg GEMM: xg[cell][m][512] f16 = A[m][:] . Wih_cell^T + bias ----------
// A: [M][KW] u32 (f16x2, row-major). Bt: [1024 n][KW] u32 (n = cell*512+g).
// Grid (16 n-tiles, 1024 m-tiles) x 256 thr. 64x64 tile, 4 waves of 32x32.
// Store-side gate permutation: gp = ((g&127)<<2)|(g>>7) so the scan's lane
// map (gate gp = tid) loads consecutive u16.
template <int KW>
__global__ __launch_bounds__(256) void xg_gemm(
    const uint32_t* __restrict__ A, const uint32_t* __restrict__ Bt,
    const float* __restrict__ biascat, uint16_t* __restrict__ xg) {
  const int n0 = blockIdx.x * 64;
  const int m0 = blockIdx.y * 64;
  const int tid = threadIdx.x;
  __shared__ uint32_t At[64][36];   // stride 36 words: 16B-aligned quads, 2-way banks
  __shared__ uint32_t Bts[64][36];
  const int lr = tid >> 2, lq = tid & 3;
  const int wave = tid >> 6, lane = tid & 63;
  const int wm = wave >> 1, wn = wave & 1;
  const int q = lane >> 4, ln16 = lane & 15;
  f32x4 acc[2][2] = {};
  for (int kb = 0; kb < KW; kb += 16) {
    uint4 av = *(const uint4*)&A[(size_t)(m0 + lr) * KW + kb + lq * 4];
    uint4 bv = *(const uint4*)&Bt[(size_t)(n0 + lr) * KW + kb + lq * 4];
    __syncthreads();  // previous iteration's fragment reads complete
    *(uint4*)&At[lr][lq * 4] = av;
    *(uint4*)&Bts[lr][lq * 4] = bv;
    __syncthreads();
#pragma unroll
    for (int mi = 0; mi < 2; mi++) {
      f16x8 af = *(const f16x8*)&At[wm * 32 + mi * 16 + ln16][q * 4];
#pragma unroll
      for (int ni = 0; ni < 2; ni++) {
        f16x8 bf = *(const f16x8*)&Bts[wn * 32 + ni * 16 + ln16][q * 4];
        acc[mi][ni] = __builtin_amdgcn_mfma_f32_16x16x32_f16(af, bf, acc[mi][ni], 0, 0, 0);
      }
    }
  }
  // D layout (verified m89/m91): col = lane&15, row = (lane>>4)*4 + reg
#pragma unroll
  for (int mi = 0; mi < 2; mi++)
#pragma unroll
    for (int ni = 0; ni < 2; ni++) {
      int n = n0 + wn * 32 + ni * 16 + ln16;
      int cell = n >> 9, g = n & 511;
      int gp = ((g & 127) << 2) | (g >> 7);  // quad-interleaved gate index
      float bs = biascat[n];
#pragma unroll
      for (int i = 0; i < 4; i++) {
        int m = m0 + wm * 32 + mi * 16 + q * 4 + i;
        float v = acc[mi][ni][i] + bs;
        xg[((size_t)cell * M_TOT + m) * 512 + gp] =
            __builtin_bit_cast(uint16_t, (_Float16)v);
      }
    }
}

// ---------- scan: gates_t = xg_t + Whh.h_{t-1} via MFMA ----------
// 128 WGs (dir*64+b) x 512 thr. Wave w owns gates gp in [64w, 64w+64); lane
// l ends with z[gp = 64w+l] via the redundant-A-row trick. Tail: unit
// j = tid>>2, gate p = tid&3; quad DPP broadcast + redundant cell update.
// One raw lgkm-barrier per step; 8-slot xg prefetch pipeline.
template <bool FINAL>
__global__ __launch_bounds__(512, 2) void scan_kernel(
    const uint16_t* __restrict__ xg, const uint32_t* __restrict__ whB,
    uint16_t* __restrict__ hout, float* __restrict__ fout) {
  const int tid = threadIdx.x;
  const int j = tid >> 2;   // hidden unit 0..127
  const int p = tid & 3;    // gate selector (i,f,g,o)
  const int w = tid >> 6;   // wave 0..7
  const int lane = tid & 63;
  const int q = lane >> 4;  // 16-lane group 0..3
  const int ln16 = lane & 15;
  const int b = blockIdx.x & 63;
  const int dir = blockIdx.x >> 6;

  __shared__ __align__(16) uint32_t hbuf[2][64];  // [parity][h f16x2]

  // B-fragments of Whh: wb[nt][kt], lane l holds Whh'[gp=64w+16nt+ln16]
  // [k=32kt+q*8+jj] (jj=0..7) = 4 consecutive u32 of whB row gp.
  f16x8 wb[4][4];
  {
    const uint32_t* wp = whB + (size_t)dir * 512 * 64;
#pragma unroll
    for (int nt = 0; nt < 4; nt++)
#pragma unroll
      for (int kt = 0; kt < 4; kt++)
        wb[nt][kt] = *(const f16x8*)&wp[(64 * w + 16 * nt + ln16) * 64 + 16 * kt + q * 4];
  }
#pragma unroll
  for (int nt = 0; nt < 4; nt++)
#pragma unroll
    for (int kt = 0; kt < 4; kt++) asm volatile("" : "+v"(wb[nt][kt]));

  // per-thread gate constants: lane p==2 computes tanh = 2*sigmoid(2z)-1
  const float kmul = (p == 2) ? (-2.0f * 1.44269504f) : -1.44269504f;
  const float gm = (p == 2) ? 2.0f : 1.0f;
  const float gb = (p == 2) ? -1.0f : 0.0f;

  const uint16_t* xgp = xg + ((size_t)dir * M_TOT + b * T_SEQ) * 512 + tid;

  if (tid < 64) hbuf[0][tid] = 0u;
  float c = 0.0f;
  const f32x4 zero4 = {0.0f, 0.0f, 0.0f, 0.0f};

  // 8-slot prefetch pipeline: slot(s) = s&7; prologue fills steps 0..3.
  uint16_t xr[8];
#pragma unroll
  for (int k = 0; k < 4; k++) {
    const int tk = dir ? (T_SEQ - 1 - k) : k;
    xr[k] = xgp[(size_t)tk * 512];
  }
  __syncthreads();  // prologue: full drain once is fine

  for (int s0 = 0; s0 < T_SEQ; s0 += 8) {
    // re-pin weights each outer iter: forbids spill/remat
#pragma unroll
    for (int nt = 0; nt < 4; nt++)
#pragma unroll
      for (int kt = 0; kt < 4; kt++) asm volatile("" : "+v"(wb[nt][kt]));
#pragma unroll
    for (int k = 0; k < 8; k++) {
      const int s = s0 + k;
      const int par = k & 1;

      // issue prefetch for step s+4 into slot (k+4)&7 (unconditional, clamped)
      {
        int sn = s + 4;
        sn = (sn < T_SEQ) ? sn : (T_SEQ - 1);
        const int tn = dir ? (T_SEQ - 1 - sn) : sn;
        xr[(k + 4) & 7] = xgp[(size_t)tn * 512];
      }

      // MFMA matvec: A-frag rows all identical = h (each 16-lane group reads
      // the same 16B h slice); acc[nt] accumulates over the 4 K-tiles.
      const uint4* hb4 = (const uint4*)&hbuf[par][0];  // 16 x uint4
      f32x4 a0 = zero4, a1 = zero4, a2 = zero4, a3 = zero4;
#pragma unroll
      for (int kt = 0; kt < 4; kt++) {
        f16x8 hk = __builtin_bit_cast(f16x8, hb4[kt * 4 + q]);
        a0 = __builtin_amdgcn_mfma_f32_16x16x32_f16(hk, wb[0][kt], a0, 0, 0, 0);
        a1 = __builtin_amdgcn_mfma_f32_16x16x32_f16(hk, wb[1][kt], a1, 0, 0, 0);
        a2 = __builtin_amdgcn_mfma_f32_16x16x32_f16(hk, wb[2][kt], a2, 0, 0, 0);
        a3 = __builtin_amdgcn_mfma_f32_16x16x32_f16(hk, wb[3][kt], a3, 0, 0, 0);
      }
      // all C rows identical -> lane l's gate (gp = 64w+l) sits in acc[q][0]
      float zs = (q & 2) ? ((q & 1) ? a3[0] : a2[0]) : ((q & 1) ? a1[0] : a0[0]);

      // fold in this lane's own xg term
      float z = zs + (float)__builtin_bit_cast(_Float16, xr[k]);

      // one transcendental per lane; tanh via sigmoid identity for p==2
      float e = __builtin_amdgcn_exp2f(z * kmul);
      float sg = __builtin_amdgcn_rcpf(1.0f + e);
      float gv = __builtin_fmaf(sg, gm, gb);

      // quad broadcast: every lane gets i,f,g,o (bitwise identical in quad)
      float gi = dppf<0x00>(gv);
      float gf = dppf<0x55>(gv);
      float gg = dppf<0xAA>(gv);
      float go = dppf<0xFF>(gv);

      c = __builtin_fmaf(gf, c, gi * gg);
      float ec = __builtin_amdgcn_exp2f(c * (-2.0f * 1.44269504f));
      float th = __builtin_fmaf(2.0f, __builtin_amdgcn_rcpf(1.0f + ec), -1.0f);
      float h = go * th;

      if (p == 0) {
        const int t = dir ? (T_SEQ - 1 - s) : s;
        uint16_t hu = __builtin_bit_cast(uint16_t, (_Float16)h);
        ((uint16_t*)(&hbuf[par ^ 1][0]))[j] = hu;
        if (FINAL) {
          fout[(size_t)(b * T_SEQ + t) * 256 + dir * 128 + j] = h;
        } else {
          hout[(size_t)(b * T_SEQ + t) * 256 + dir * 128 + j] = hu;
        }
      }
      // RAW barrier: order ONLY the LDS h-write (lgkmcnt), leave the global
      // prefetch loads / output stores in flight (counted vmcnt at use).
      asm volatile("s_waitcnt lgkmcnt(0)" ::: "memory");
      __builtin_amdgcn_s_barrier();
      asm volatile("" ::: "memory");  // nothing hoists above the barrier
    }
  }
}

extern "C" void kernel_launch(void* const* d_in, const int* in_sizes, int n_in,
                              void* d_out, int out_size, void* d_ws, size_t ws_size,
                              hipStream_t stream) {
  const float* x = (const float*)d_in[0];
  const float* Wih_fw1 = (const float*)d_in[2];
  const float* Whh_fw1 = (const float*)d_in[3];
  const float* bih_fw1 = (const float*)d_in[4];
  const float* bhh_fw1 = (const float*)d_in[5];
  const float* Wih_bw1 = (const float*)d_in[6];
  const float* Whh_bw1 = (const float*)d_in[7];
  const float* bih_bw1 = (const float*)d_in[8];
  const float* bhh_bw1 = (const float*)d_in[9];
  const float* Wih_fw2 = (const float*)d_in[10];
  const float* Whh_fw2 = (const float*)d_in[11];
  const float* bih_fw2 = (const float*)d_in[12];
  const float* bhh_fw2 = (const float*)d_in[13];
  const float* Wih_bw2 = (const float*)d_in[14];
  const float* Whh_bw2 = (const float*)d_in[15];
  const float* bih_bw2 = (const float*)d_in[16];
  const float* bhh_bw2 = (const float*)d_in[17];

  uint8_t* ws = (uint8_t*)d_ws;
  // ws layout (bytes):
  //   0        : whbuf   [4 cells][512 gp][64 kw] u32   512 KB
  //   524288   : btbuf1  [2*512][64]  u32               256 KB
  //   786432   : btbuf2  [2*512][128] u32               512 KB
  //   1310720  : biascat [2 layers][1024] f32             8 KB
  //   2097152  : xf16    [M][64] u32                     16 MB
  //   18874368 : out1    [M][128] u32 (f16x2)            32 MB
  //   52428800 : xg      [2][M][512] f16                128 MB
  uint32_t* whbuf = (uint32_t*)(ws + 0);
  uint32_t* btbuf1 = (uint32_t*)(ws + 524288);
  uint32_t* btbuf2 = (uint32_t*)(ws + 786432);
  float* biascat = (float*)(ws + 1310720);
  uint32_t* xf16 = (uint32_t*)(ws + 2097152);
  uint32_t* out1 = (uint32_t*)(ws + 18874368);
  uint16_t* xgbuf = (uint16_t*)(ws + 52428800);
  float* fout = (float*)d_out;

  // --- weight / bias / input packing ---
  prep_whB<<<128, 256, 0, stream>>>(Whh_fw1, whbuf + 0 * 32768);
  prep_whB<<<128, 256, 0, stream>>>(Whh_bw1, whbuf + 1 * 32768);
  prep_whB<<<128, 256, 0, stream>>>(Whh_fw2, whbuf + 2 * 32768);
  prep_whB<<<128, 256, 0, stream>>>(Whh_bw2, whbuf + 3 * 32768);
  prep_bt<64><<<128, 256, 0, stream>>>(Wih_fw1, btbuf1 + 0);
  prep_bt<64><<<128, 256, 0, stream>>>(Wih_bw1, btbuf1 + 512 * 64);
  prep_bt<128><<<256, 256, 0, stream>>>(Wih_fw2, btbuf2 + 0);
  prep_bt<128><<<256, 256, 0, stream>>>(Wih_bw2, btbuf2 + 512 * 128);
  prep_biasc<<<2, 256, 0, stream>>>(bih_fw1, bhh_fw1, biascat + 0);
  prep_biasc<<<2, 256, 0, stream>>>(bih_bw1, bhh_bw1, biascat + 512);
  prep_biasc<<<2, 256, 0, stream>>>(bih_fw2, bhh_fw2, biascat + 1024);
  prep_biasc<<<2, 256, 0, stream>>>(bih_bw2, bhh_bw2, biascat + 1536);
  prep_x<<<(B_SZ * T_SEQ * 64) / 256, 256, 0, stream>>>((const float2*)x, xf16);

  // --- layer 1: xg GEMM + scan ---
  xg_gemm<64><<<dim3(16, 1024), 256, 0, stream>>>(xf16, btbuf1, biascat, xgbuf);
  scan_kernel<false><<<128, 512, 0, stream>>>(xgbuf, whbuf + 0, (uint16_t*)out1, nullptr);

  // --- layer 2: xg GEMM (reads out1) + scan -> d_out ---
  xg_gemm<128><<<dim3(16, 1024), 256, 0, stream>>>(out1, btbuf2, biascat + 1024, xgbuf);
  scan_kernel<true><<<128, 512, 0, stream>>>(xgbuf, whbuf + 2 * 32768, nullptr, fout);
}